// Round 4
// baseline (699.239 us; speedup 1.0000x reference)
//
#include <hip/hip_runtime.h>

// SNG: sn[b,l] = 8-step majority chain (reference scan unrolled):
//   v_0 = 0; v_{i+1} = maj(x[b,i], v_i, r[b,i,l+i]); sn[b,l] = v_8
// maj(1,v,r) = v|r ; maj(0,v,r) = v&r  -> uniform branch per row (nb is
// block-uniform), 1 VALU op per element.
//
// v4: all global loads 16B-aligned. The per-row +i diagonal shift is absorbed
// by staging each row-chunk in LDS (aligned global_load_lds dwordx4) and
// reading LDS at index +i (stride-1 across lanes -> conflict-free).

#define BATCH 1024
#define PBITS 8
#define LBITS 16384
#define TLEN (PBITS + LBITS)   // 16392 dwords per r-row (16392 % 4 == 0 -> rows 16B-aligned)

#define CHUNK 4096             // output dwords per block
#define STAGE_DW 4104          // CHUNK + 7 needed, rounded to /8; stays in-bounds (<= TLEN)

typedef const __attribute__((address_space(1))) void gvoid;
typedef __attribute__((address_space(3))) void lvoid;

__global__ __launch_bounds__(256) void sng_kernel(const int* __restrict__ num,
                                                  const int* __restrict__ r,
                                                  int* __restrict__ out) {
    __shared__ int lds[STAGE_DW];          // 16416 B

    const int t = threadIdx.x;             // 0..255
    const int b = blockIdx.x >> 2;         // 4 blocks per batch row
    const int jb = (blockIdx.x & 3) << 12; // chunk base dword within row

    const int nb = num[b];                 // wave-uniform -> SGPR
    const int* rowbase = r + (size_t)b * (PBITS * TLEN) + jb;  // 16B-aligned

    int v[16];
#pragma unroll
    for (int k = 0; k < 16; ++k) v[k] = 0;

#pragma unroll
    for (int i = 0; i < PBITS; ++i) {
        const int* src = rowbase + i * TLEN;   // 16B-aligned (TLEN%4==0)
        // stage dwords [jb .. jb+4103] of row i: 1026 aligned int4 loads,
        // direct global->LDS (no VGPR round trip)
#pragma unroll
        for (int k = 0; k < 4; ++k)
            __builtin_amdgcn_global_load_lds((gvoid*)(src + 4 * (t + 256 * k)),
                                             (lvoid*)(&lds[4 * (t + 256 * k)]),
                                             16, 0, 0);
        if (t < 2)
            __builtin_amdgcn_global_load_lds((gvoid*)(src + 4 * (1024 + t)),
                                             (lvoid*)(&lds[4 * (1024 + t)]),
                                             16, 0, 0);
        __syncthreads();                       // drains vmcnt, data visible

        // thread t owns outputs jb + t + 256k; row dword needed = pos + i
        const int* lp = &lds[t + i];           // lanes stride 1 dword: conflict-free
        if ((nb >> i) & 1) {
#pragma unroll
            for (int k = 0; k < 16; ++k) v[k] |= lp[256 * k];  // ds_read_b32 + v_or
        } else {
#pragma unroll
            for (int k = 0; k < 16; ++k) v[k] &= lp[256 * k];  // ds_read_b32 + v_and
        }
        __syncthreads();                       // protect lds before next-row stage
    }

    int* ob = out + (size_t)b * LBITS + jb + t;
#pragma unroll
    for (int k = 0; k < 16; ++k)
        __builtin_nontemporal_store(v[k], ob + 256 * k);  // 256B contiguous per wave-inst
}

extern "C" void kernel_launch(void* const* d_in, const int* in_sizes, int n_in,
                              void* d_out, int out_size, void* d_ws, size_t ws_size,
                              hipStream_t stream) {
    const int* num = (const int*)d_in[0];   // [B] int32
    const int* r   = (const int*)d_in[1];   // [B, P, P+L] int32 (0/1)
    int* out = (int*)d_out;                 // [B, L] int32 (0/1)

    const int blocks = BATCH * 4;           // 4096 blocks x 256 threads, 16 out/thread
    sng_kernel<<<blocks, 256, 0, stream>>>(num, r, out);
}